// Round 10
// baseline (155.927 us; speedup 1.0000x reference)
//
#include <hip/hip_runtime.h>
#include <hip/hip_bf16.h>

#define S 1024
#define C 384
#define NC 32
#define SHIFT 0.3f
#define MAGIC 0x5EEDF00Du

typedef __attribute__((ext_vector_type(4))) float f32x4;
typedef __attribute__((ext_vector_type(8))) short short8;

// f32 -> bf16 (round-to-nearest-even), raw-bit version (finite inputs only)
__device__ __forceinline__ unsigned int f2bf(float x) {
  unsigned int u = __builtin_bit_cast(unsigned int, x);
  unsigned int rb = ((u >> 16) & 1u) + 0x7fffu;
  return (u + rb) >> 16;
}
__device__ __forceinline__ unsigned int f2bf2(float lo, float hi) {
  return f2bf(lo) | (f2bf(hi) << 16);
}
__device__ __forceinline__ unsigned long long pack2f(float a, float b) {
  return (unsigned long long)__builtin_bit_cast(unsigned int, a) |
         ((unsigned long long)__builtin_bit_cast(unsigned int, b) << 32);
}

// async global->LDS, 16B per lane; LDS dest is wave-uniform base + lane*16
__device__ __forceinline__ void gld16(void* lds, const void* g) {
  __builtin_amdgcn_global_load_lds(
      (const __attribute__((address_space(1))) void*)g,
      (__attribute__((address_space(3))) void*)lds, 16, 0, 0);
}

// ONE plain launch, 544 blocks (all co-resident: LDS 39.2KB -> 4 blocks/CU, VGPR
// capped at 128 by launch_bounds). Diagonal tile blocks (ty==tx, 64 of them) prep
// their 64-row panel (bf16 fnb + Eb/Pb/rowdot) to global, fence, set panel flag.
// All blocks spin on their two panel flags, then run the R7 triangular pair core.
// Block 0 reduces via the R9-validated done-flag spinner.
__global__ __launch_bounds__(256, 4) void k_one(
    const float* __restrict__ f, const float* __restrict__ p,
    unsigned int* __restrict__ fnb, unsigned int* __restrict__ Eb,
    unsigned int* __restrict__ Pb, float* __restrict__ rowdot,
    unsigned int* __restrict__ pflags, unsigned int* __restrict__ dflags,
    unsigned long long* __restrict__ partials, float* __restrict__ out) {
  __shared__ unsigned short As[64 * 72];
  __shared__ unsigned short Bs[64 * 72];
  __shared__ unsigned short Ese[64 * 40];
  __shared__ unsigned short Esp[64 * 40];
  __shared__ unsigned short Ele[64 * 40];
  __shared__ unsigned short Elp[64 * 40];
  __shared__ float invnL[64];
  __shared__ float4 red[4];

  const int tid = threadIdx.x;
  const int lane = tid & 63;
  const int wave = tid >> 6;
  const int lan = lane & 15, quad = lane >> 4;
  const int n = blockIdx.y;
  const int bid = blockIdx.y * 136 + blockIdx.x;

  // triangular tile decode: bx -> (ty, tx), tx >= ty; rem==0 => diagonal
  int rem = blockIdx.x, ty = 0;
  while (rem >= 16 - ty) {
    rem -= 16 - ty;
    ++ty;
  }
  const int tx = ty + rem;
  const int sBase = ty * 64, lBase = tx * 64;

  // ---------- producer phase: diagonal blocks prep panel ty ----------
  if (ty == tx) {
    const int prow = tid >> 2, q = tid & 3;  // 64 rows, 4 threads/row
    const int grow = n * S + sBase + prow;
    const float* fr = f + (size_t)grow * C + q * 96;
    // pass 1: sum of squares (96 floats/thread)
    float ss = 0.f;
#pragma unroll
    for (int j = 0; j < 24; ++j) {
      float4 v = ((const float4*)fr)[j];
      ss = fmaf(v.x, v.x, fmaf(v.y, v.y, fmaf(v.z, v.z, fmaf(v.w, v.w, ss))));
    }
    ss += __shfl_xor(ss, 1, 64);
    ss += __shfl_xor(ss, 2, 64);
    if (q == 0) invnL[prow] = 1.f / fmaxf(sqrtf(ss), 1e-12f);
    __syncthreads();
    // pass 2: scale + pack bf16 -> fnb (L2-hot re-read)
    {
      float sa = invnL[prow];
      unsigned int* dst = fnb + (size_t)grow * 192 + q * 48;
#pragma unroll
      for (int j = 0; j < 12; ++j) {
        float4 a = ((const float4*)fr)[2 * j];
        float4 b = ((const float4*)fr)[2 * j + 1];
        uint4 o = make_uint4(f2bf2(a.x * sa, a.y * sa), f2bf2(a.z * sa, a.w * sa),
                             f2bf2(b.x * sa, b.y * sa), f2bf2(b.z * sa, b.w * sa));
        ((uint4*)dst)[j] = o;
      }
    }
    // E/P pack + rowdot: 4 threads/row, 8 classes each
    {
      const float* pr = p + (size_t)grow * NC + q * 8;
      float4 a = *(const float4*)pr;
      float4 b = *(const float4*)(pr + 4);
      float e0 = __expf(a.x), e1 = __expf(a.y), e2 = __expf(a.z), e3 = __expf(a.w);
      float e4 = __expf(b.x), e5 = __expf(b.y), e6 = __expf(b.z), e7 = __expf(b.w);
      *(uint4*)(Eb + grow * 16 + q * 4) =
          make_uint4(f2bf2(e0, e1), f2bf2(e2, e3), f2bf2(e4, e5), f2bf2(e6, e7));
      *(uint4*)(Pb + grow * 16 + q * 4) =
          make_uint4(f2bf2(a.x, a.y), f2bf2(a.z, a.w), f2bf2(b.x, b.y), f2bf2(b.z, b.w));
      float rd = e0 * a.x + e1 * a.y + e2 * a.z + e3 * a.w +
                 e4 * b.x + e5 * b.y + e6 * b.z + e7 * b.w;
      rd += __shfl_xor(rd, 1, 64);
      rd += __shfl_xor(rd, 2, 64);
      if (q == 0) rowdot[grow] = rd;
    }
    __syncthreads();  // all stores retired (barrier drains vmcnt)
    if (tid == 0) {
      __threadfence();  // L2 writeback -> device-visible
      atomicExch(&pflags[n * 16 + ty], MAGIC);
    }
  }

  // ---------- consumer phase: wait for both panels ----------
  if (tid == 0) {
    while (atomicOr(&pflags[n * 16 + ty], 0u) != MAGIC ||
           atomicOr(&pflags[n * 16 + tx], 0u) != MAGIC)
      __builtin_amdgcn_s_sleep(2);
  }
  __syncthreads();
  __threadfence();

  // ---------- R7 triangular pair core ----------
  const int r8 = lane >> 3, c8 = lane & 7;
  const char* gA = (const char*)fnb +
                   ((size_t)(n * S + sBase + 16 * wave + r8)) * 768 + ((c8 ^ r8) << 4);
  const char* gB = (const char*)fnb +
                   ((size_t)(n * S + lBase + 16 * wave + r8)) * 768 + ((c8 ^ r8) << 4);
  char* lA = (char*)As + (16 * wave) * 128;
  char* lB = (char*)Bs + (16 * wave) * 128;

  {
    int row = tid >> 2, q = tid & 3;
    *(uint4*)(&Ese[row * 40 + q * 8]) =
        *(const uint4*)(Eb + (size_t)(n * S + sBase + row) * 16 + q * 4);
    *(uint4*)(&Esp[row * 40 + q * 8]) =
        *(const uint4*)(Pb + (size_t)(n * S + sBase + row) * 16 + q * 4);
    *(uint4*)(&Ele[row * 40 + q * 8]) =
        *(const uint4*)(Eb + (size_t)(n * S + lBase + row) * 16 + q * 4);
    *(uint4*)(&Elp[row * 40 + q * 8]) =
        *(const uint4*)(Pb + (size_t)(n * S + lBase + row) * 16 + q * 4);
  }

  f32x4 acc[4];
#pragma unroll
  for (int j = 0; j < 4; ++j) acc[j] = (f32x4){0.f, 0.f, 0.f, 0.f};

  for (int kt = 0; kt < 6; ++kt) {
    gld16(lA, gA + kt * 128);
    gld16(lA + 8 * 128, gA + 8 * 768 + kt * 128);
    gld16(lB, gB + kt * 128);
    gld16(lB + 8 * 128, gB + 8 * 768 + kt * 128);
    __syncthreads();
#pragma unroll
    for (int ks = 0; ks < 2; ++ks) {
      short8 af, bfr[4];
      af = *(const short8*)((const char*)As + (16 * wave + lan) * 128 +
                            ((((ks << 2) | quad) ^ (lan & 7)) << 4));
#pragma unroll
      for (int t = 0; t < 4; ++t)
        bfr[t] = *(const short8*)((const char*)Bs + (t * 16 + lan) * 128 +
                                  ((((ks << 2) | quad) ^ (lan & 7)) << 4));
#pragma unroll
      for (int j = 0; j < 4; ++j)
        acc[j] = __builtin_amdgcn_mfma_f32_16x16x32_bf16(af, bfr[j], acc[j], 0, 0, 0);
    }
    __syncthreads();
  }

  // epilogue: dual EP mini-GEMMs + weighted triangular reduction
  // C/D layout: row(m=s) = quad*4+reg, col(n=l) = lan
  short8 eas, ps;
  {
    int row = 16 * wave + lan;
    eas = *(const short8*)(&Ese[row * 40 + quad * 8]);
    ps = *(const short8*)(&Esp[row * 40 + quad * 8]);
  }
  float rd_s[4];
  {
    int gs0 = n * S + sBase + 16 * wave + quad * 4;
#pragma unroll
    for (int r = 0; r < 4; ++r) rd_s[r] = rowdot[gs0 + r];
  }

  float pos_s = 0.f, neg_s = 0.f, posc = 0.f, negc = 0.f;
#pragma unroll
  for (int j = 0; j < 4; ++j) {
    short8 pl = *(const short8*)(&Elp[(j * 16 + lan) * 40 + quad * 8]);
    short8 eal = *(const short8*)(&Ele[(j * 16 + lan) * 40 + quad * 8]);
    f32x4 z = (f32x4){0.f, 0.f, 0.f, 0.f};
    f32x4 ep1 = __builtin_amdgcn_mfma_f32_16x16x32_bf16(eas, pl, z, 0, 0, 0);
    f32x4 ep2 = __builtin_amdgcn_mfma_f32_16x16x32_bf16(ps, eal, z, 0, 0, 0);
    int gl = lBase + j * 16 + lan;
    float rd_l = rowdot[n * S + gl];
#pragma unroll
    for (int r = 0; r < 4; ++r) {
      int gs = sBase + 16 * wave + quad * 4 + r;
      float w1 = (gl >= gs) ? 1.f : 0.f;
      float w2 = (gl > gs) ? 1.f : 0.f;
      float fc = acc[j][r] - SHIFT;
      float contrib = w1 * (rd_s[r] - ep1[r]) + w2 * (rd_l - ep2[r]);
      float cnt = w1 + w2;
      if (fc > 0.f) {
        pos_s = fmaf(fc, contrib, pos_s);
        posc += cnt;
      } else if (fc < 0.f) {
        neg_s = fmaf(fc, contrib, neg_s);
        negc += cnt;
      }
    }
  }
#pragma unroll
  for (int m = 32; m >= 1; m >>= 1) {
    pos_s += __shfl_xor(pos_s, m, 64);
    neg_s += __shfl_xor(neg_s, m, 64);
    posc += __shfl_xor(posc, m, 64);
    negc += __shfl_xor(negc, m, 64);
  }
  if (lane == 0) {
    atomicExch(&partials[(bid * 4 + wave) * 2], pack2f(pos_s, neg_s));
    atomicExch(&partials[(bid * 4 + wave) * 2 + 1], pack2f(posc, negc));
  }
  __syncthreads();
  if (tid == 0) {
    __threadfence();
    atomicExch(&dflags[bid], MAGIC);
  }

  // ---------- block 0: lone spinner, then final reduction ----------
  if (bid == 0) {
    bool ok;
    do {
      ok = true;
      for (int idx = tid; idx < 544; idx += 256)
        ok &= (atomicOr(&dflags[idx], 0u) == MAGIC);
      if (!ok) __builtin_amdgcn_s_sleep(8);
    } while (!__syncthreads_and(ok));

    float4 s = make_float4(0.f, 0.f, 0.f, 0.f);
    for (int idx = tid; idx < 2176; idx += 256) {
      unsigned long long u1 = atomicOr(&partials[idx * 2], 0ull);
      unsigned long long u2 = atomicOr(&partials[idx * 2 + 1], 0ull);
      s.x += __builtin_bit_cast(float, (unsigned int)(u1 & 0xffffffffu));
      s.y += __builtin_bit_cast(float, (unsigned int)(u1 >> 32));
      s.z += __builtin_bit_cast(float, (unsigned int)(u2 & 0xffffffffu));
      s.w += __builtin_bit_cast(float, (unsigned int)(u2 >> 32));
    }
#pragma unroll
    for (int m = 32; m >= 1; m >>= 1) {
      s.x += __shfl_xor(s.x, m, 64);
      s.y += __shfl_xor(s.y, m, 64);
      s.z += __shfl_xor(s.z, m, 64);
      s.w += __shfl_xor(s.w, m, 64);
    }
    if ((tid & 63) == 0) red[tid >> 6] = s;
    __syncthreads();
    if (tid == 0) {
      float4 t = red[0];
#pragma unroll
      for (int w = 1; w < 4; ++w) {
        t.x += red[w].x;
        t.y += red[w].y;
        t.z += red[w].z;
        t.w += red[w].w;
      }
      out[0] = t.x / t.z;
      out[1] = t.y / t.w;
    }
  }
}

extern "C" void kernel_launch(void* const* d_in, const int* in_sizes, int n_in,
                              void* d_out, int out_size, void* d_ws, size_t ws_size,
                              hipStream_t stream) {
  const float* f = (const float*)d_in[0];  // feats [4,32,32,384] f32
  const float* p = (const float*)d_in[1];  // p_class [4,32,32,32] f32 (log-probs)
  float* out = (float*)d_out;              // [pos, neg]
  char* ws = (char*)d_ws;
  // ws layout (bytes): pflags u32[64] @0 | dflags u32[544] @1024 |
  // partials u64[4352] @8192 | rowdot f32[4096] @49152 | fnb u32[786432] @65536 |
  // Eb u32[65536] @3211264 | Pb u32[65536] @3473408
  unsigned int* pflags = (unsigned int*)(ws);
  unsigned int* dflags = (unsigned int*)(ws + 1024);
  unsigned long long* partials = (unsigned long long*)(ws + 8192);
  float* rowdot = (float*)(ws + 49152);
  unsigned int* fnb = (unsigned int*)(ws + 65536);
  unsigned int* Eb = (unsigned int*)(ws + 3211264);
  unsigned int* Pb = (unsigned int*)(ws + 3473408);

  k_one<<<dim3(136, 4), dim3(256), 0, stream>>>(f, p, fnb, Eb, Pb, rowdot,
                                                pflags, dflags, partials, out);
}

// Round 11
// 80.967 us; speedup vs baseline: 1.9258x; 1.9258x over previous
//
#include <hip/hip_runtime.h>
#include <hip/hip_bf16.h>

#define S 1024
#define C 384
#define NC 32
#define SHIFT 0.3f
#define MAGIC 0x5EEDF00Du

typedef __attribute__((ext_vector_type(4))) float f32x4;
typedef __attribute__((ext_vector_type(8))) short short8;

// f32 -> bf16 (round-to-nearest-even), raw-bit version (finite inputs only)
__device__ __forceinline__ unsigned int f2bf(float x) {
  unsigned int u = __builtin_bit_cast(unsigned int, x);
  unsigned int rb = ((u >> 16) & 1u) + 0x7fffu;
  return (u + rb) >> 16;
}
__device__ __forceinline__ unsigned int f2bf2(float lo, float hi) {
  return f2bf(lo) | (f2bf(hi) << 16);
}
__device__ __forceinline__ unsigned long long pack2f(float a, float b) {
  return (unsigned long long)__builtin_bit_cast(unsigned int, a) |
         ((unsigned long long)__builtin_bit_cast(unsigned int, b) << 32);
}

// async global->LDS, 16B per lane; LDS dest is wave-uniform base + lane*16
__device__ __forceinline__ void gld16(void* lds, const void* g) {
  __builtin_amdgcn_global_load_lds(
      (const __attribute__((address_space(1))) void*)g,
      (__attribute__((address_space(3))) void*)lds, 16, 0, 0);
}

// ---- prep: normalize f -> bf16 fnb; exp(p)/p -> bf16 Eb/Pb; rowdot (R7-proven) ----
__global__ __launch_bounds__(256) void k_prep(const float* __restrict__ f,
                                              const float* __restrict__ p,
                                              unsigned int* __restrict__ fnb,
                                              unsigned int* __restrict__ Eb,
                                              unsigned int* __restrict__ Pb,
                                              float* __restrict__ rowdot) {
  if (blockIdx.x < 1024) {
    int lane = threadIdx.x & 63;
    int row = blockIdx.x * 4 + (threadIdx.x >> 6);
    const float* fr = f + (size_t)row * C;
    float2 v[3];
    float ss = 0.f;
#pragma unroll
    for (int j = 0; j < 3; ++j) {
      v[j] = *(const float2*)(fr + 2 * lane + 128 * j);
      ss = fmaf(v[j].x, v[j].x, fmaf(v[j].y, v[j].y, ss));
    }
#pragma unroll
    for (int m = 32; m >= 1; m >>= 1) ss += __shfl_xor(ss, m, 64);
    float s = 1.f / fmaxf(sqrtf(ss), 1e-12f);
    unsigned int* outr = fnb + (size_t)row * (C / 2);
#pragma unroll
    for (int j = 0; j < 3; ++j) outr[lane + 64 * j] = f2bf2(v[j].x * s, v[j].y * s);
  } else {
    int t = (blockIdx.x - 1024) * 256 + threadIdx.x;  // [0, 16384)
    int r = t >> 2, q = t & 3;
    const float* pr = p + (size_t)r * NC + q * 8;
    float4 a = *(const float4*)pr;
    float4 b = *(const float4*)(pr + 4);
    float ea0 = __expf(a.x), ea1 = __expf(a.y), ea2 = __expf(a.z), ea3 = __expf(a.w);
    float eb0 = __expf(b.x), eb1 = __expf(b.y), eb2 = __expf(b.z), eb3 = __expf(b.w);
    uint4 ue = make_uint4(f2bf2(ea0, ea1), f2bf2(ea2, ea3), f2bf2(eb0, eb1), f2bf2(eb2, eb3));
    uint4 up = make_uint4(f2bf2(a.x, a.y), f2bf2(a.z, a.w), f2bf2(b.x, b.y), f2bf2(b.z, b.w));
    *(uint4*)(Eb + r * 16 + q * 4) = ue;
    *(uint4*)(Pb + r * 16 + q * 4) = up;
    float s = ea0 * a.x + ea1 * a.y + ea2 * a.z + ea3 * a.w +
              eb0 * b.x + eb1 * b.y + eb2 * b.z + eb3 * b.w;
    s += __shfl_xor(s, 1, 64);
    s += __shfl_xor(s, 2, 64);
    if (q == 0) rowdot[r] = s;
  }
}

// ---- pairwise, triangular 64x64 tiles, ONE barrier total ----
// B panel: all 6 K-chunks staged upfront via gld16 into 48KB LDS (XOR swizzle/slab).
// A fragments: 12 direct global_load_dwordx4 into registers (wave-private rows).
// K-loop: pure ds_read_b128 + MFMA, no barriers. Epilogue E/P fragments direct
// from global. Final reduce fused via R9-validated lone block-0 spinner.
__global__ __launch_bounds__(256) void k_pair(
    const unsigned short* __restrict__ fnb, const unsigned short* __restrict__ Eb,
    const unsigned short* __restrict__ Pb, const float* __restrict__ rowdot,
    unsigned int* __restrict__ dflags, unsigned long long* __restrict__ partials,
    float* __restrict__ out) {
  __shared__ unsigned short Bs[6 * 64 * 64];  // 48 KB: 6 slabs of [64 rows][64 cols]
  __shared__ float4 red[4];

  const int tid = threadIdx.x;
  const int lane = tid & 63;
  const int wave = tid >> 6;
  const int lan = lane & 15, quad = lane >> 4;
  const int n = blockIdx.y;
  const int bid = blockIdx.y * 136 + blockIdx.x;

  // triangular tile decode: bx -> (ty, tx), tx >= ty
  int rem = blockIdx.x, ty = 0;
  while (rem >= 16 - ty) {
    rem -= 16 - ty;
    ++ty;
  }
  const int tx = ty + rem;
  const int sBase = ty * 64, lBase = tx * 64;

  // A fragments: rows sBase + 16*wave + lan, all 12 K-steps, direct to registers
  short8 af[12];
  {
    const unsigned short* baseA = fnb + (size_t)(n * S + sBase + 16 * wave + lan) * C + quad * 8;
#pragma unroll
    for (int ks = 0; ks < 12; ++ks) af[ks] = *(const short8*)(baseA + ks * 32);
  }

  // B panel staging: slab kt holds cols [kt*64, kt*64+64) of rows lBase..lBase+64,
  // XOR-swizzled: slot chunk c holds global chunk c^(row&7). 2 gld16/slab/wave.
  {
    const int r8 = lane >> 3, c8 = lane & 7;
    const char* gB = (const char*)fnb +
                     ((size_t)(n * S + lBase + 16 * wave + r8)) * 768 + ((c8 ^ r8) << 4);
    char* lB = (char*)Bs + (16 * wave) * 128;
#pragma unroll
    for (int kt = 0; kt < 6; ++kt) {
      gld16(lB + kt * 8192, gB + kt * 128);
      gld16(lB + kt * 8192 + 1024, gB + 8 * 768 + kt * 128);
    }
  }
  __syncthreads();  // single drain: all A-register loads + B staging complete

  f32x4 acc[4];
#pragma unroll
  for (int j = 0; j < 4; ++j) acc[j] = (f32x4){0.f, 0.f, 0.f, 0.f};

  // barrier-free K loop: 12 steps of 4 ds_read_b128 + 4 MFMA
#pragma unroll
  for (int kt = 0; kt < 6; ++kt) {
#pragma unroll
    for (int ks = 0; ks < 2; ++ks) {
      short8 bfr[4];
#pragma unroll
      for (int t = 0; t < 4; ++t)
        bfr[t] = *(const short8*)((const char*)Bs + kt * 8192 + (t * 16 + lan) * 128 +
                                  ((((ks << 2) | quad) ^ (lan & 7)) << 4));
#pragma unroll
      for (int j = 0; j < 4; ++j)
        acc[j] = __builtin_amdgcn_mfma_f32_16x16x32_bf16(af[kt * 2 + ks], bfr[j], acc[j], 0, 0, 0);
    }
  }

  // epilogue: dual EP mini-GEMMs (fragments direct from global) + triangular reduce
  // C/D layout: row(m=s) = quad*4+reg, col(n=l) = lan
  short8 eas, ps;
  {
    const unsigned short* be = Eb + (size_t)(n * S + sBase + 16 * wave + lan) * NC + quad * 8;
    const unsigned short* bp = Pb + (size_t)(n * S + sBase + 16 * wave + lan) * NC + quad * 8;
    eas = *(const short8*)be;
    ps = *(const short8*)bp;
  }
  float rd_s[4];
  {
    int gs0 = n * S + sBase + 16 * wave + quad * 4;
#pragma unroll
    for (int r = 0; r < 4; ++r) rd_s[r] = rowdot[gs0 + r];
  }

  float pos_s = 0.f, neg_s = 0.f, posc = 0.f, negc = 0.f;
#pragma unroll
  for (int j = 0; j < 4; ++j) {
    const unsigned short* bl = Pb + (size_t)(n * S + lBase + j * 16 + lan) * NC + quad * 8;
    const unsigned short* el = Eb + (size_t)(n * S + lBase + j * 16 + lan) * NC + quad * 8;
    short8 pl = *(const short8*)bl;
    short8 eal = *(const short8*)el;
    f32x4 z = (f32x4){0.f, 0.f, 0.f, 0.f};
    f32x4 ep1 = __builtin_amdgcn_mfma_f32_16x16x32_bf16(eas, pl, z, 0, 0, 0);
    f32x4 ep2 = __builtin_amdgcn_mfma_f32_16x16x32_bf16(ps, eal, z, 0, 0, 0);
    int gl = lBase + j * 16 + lan;
    float rd_l = rowdot[n * S + gl];
#pragma unroll
    for (int r = 0; r < 4; ++r) {
      int gs = sBase + 16 * wave + quad * 4 + r;
      float w1 = (gl >= gs) ? 1.f : 0.f;
      float w2 = (gl > gs) ? 1.f : 0.f;
      float fc = acc[j][r] - SHIFT;
      float contrib = w1 * (rd_s[r] - ep1[r]) + w2 * (rd_l - ep2[r]);
      float cnt = w1 + w2;
      if (fc > 0.f) {
        pos_s = fmaf(fc, contrib, pos_s);
        posc += cnt;
      } else if (fc < 0.f) {
        neg_s = fmaf(fc, contrib, neg_s);
        negc += cnt;
      }
    }
  }
#pragma unroll
  for (int m = 32; m >= 1; m >>= 1) {
    pos_s += __shfl_xor(pos_s, m, 64);
    neg_s += __shfl_xor(neg_s, m, 64);
    posc += __shfl_xor(posc, m, 64);
    negc += __shfl_xor(negc, m, 64);
  }
  if (lane == 0) {
    atomicExch(&partials[(bid * 4 + wave) * 2], pack2f(pos_s, neg_s));
    atomicExch(&partials[(bid * 4 + wave) * 2 + 1], pack2f(posc, negc));
  }
  __syncthreads();
  if (tid == 0) {
    __threadfence();
    atomicExch(&dflags[bid], MAGIC);
  }

  // block 0: lone spinner (R9-validated), then final reduction
  if (bid == 0) {
    bool ok;
    do {
      ok = true;
      for (int idx = tid; idx < 544; idx += 256)
        ok &= (atomicOr(&dflags[idx], 0u) == MAGIC);
      if (!ok) __builtin_amdgcn_s_sleep(8);
    } while (!__syncthreads_and(ok));

    float4 s = make_float4(0.f, 0.f, 0.f, 0.f);
    for (int idx = tid; idx < 2176; idx += 256) {
      unsigned long long u1 = atomicOr(&partials[idx * 2], 0ull);
      unsigned long long u2 = atomicOr(&partials[idx * 2 + 1], 0ull);
      s.x += __builtin_bit_cast(float, (unsigned int)(u1 & 0xffffffffu));
      s.y += __builtin_bit_cast(float, (unsigned int)(u1 >> 32));
      s.z += __builtin_bit_cast(float, (unsigned int)(u2 & 0xffffffffu));
      s.w += __builtin_bit_cast(float, (unsigned int)(u2 >> 32));
    }
#pragma unroll
    for (int m = 32; m >= 1; m >>= 1) {
      s.x += __shfl_xor(s.x, m, 64);
      s.y += __shfl_xor(s.y, m, 64);
      s.z += __shfl_xor(s.z, m, 64);
      s.w += __shfl_xor(s.w, m, 64);
    }
    if ((tid & 63) == 0) red[tid >> 6] = s;
    __syncthreads();
    if (tid == 0) {
      float4 t = red[0];
#pragma unroll
      for (int w = 1; w < 4; ++w) {
        t.x += red[w].x;
        t.y += red[w].y;
        t.z += red[w].z;
        t.w += red[w].w;
      }
      out[0] = t.x / t.z;
      out[1] = t.y / t.w;
    }
  }
}

extern "C" void kernel_launch(void* const* d_in, const int* in_sizes, int n_in,
                              void* d_out, int out_size, void* d_ws, size_t ws_size,
                              hipStream_t stream) {
  const float* f = (const float*)d_in[0];  // feats [4,32,32,384] f32
  const float* p = (const float*)d_in[1];  // p_class [4,32,32,32] f32 (log-probs)
  float* out = (float*)d_out;              // [pos, neg]
  char* ws = (char*)d_ws;
  // ws layout (bytes): dflags u32[544] @0 | partials u64[4352] @4096 |
  // rowdot f32[4096] @40960 | fnb u32[786432] @57344 | Eb @3203072 | Pb @3465216
  unsigned int* dflags = (unsigned int*)(ws);
  unsigned long long* partials = (unsigned long long*)(ws + 4096);
  float* rowdot = (float*)(ws + 40960);
  unsigned int* fnb = (unsigned int*)(ws + 57344);
  unsigned int* Eb = (unsigned int*)(ws + 3203072);
  unsigned int* Pb = (unsigned int*)(ws + 3465216);

  k_prep<<<dim3(1088), dim3(256), 0, stream>>>(f, p, fnb, Eb, Pb, rowdot);
  k_pair<<<dim3(136, 4), dim3(256), 0, stream>>>(
      (const unsigned short*)fnb, (const unsigned short*)Eb, (const unsigned short*)Pb,
      rowdot, dflags, partials, out);
}